// Round 2
// baseline (199.163 us; speedup 1.0000x reference)
//
#include <hip/hip_runtime.h>
#include <math.h>

// QuGCN: batched 8-qubit statevector sim, gate-fused version.
// sample b = column b of x; amplitude s = (lane<<2)|r ; wire q <-> bit p=7-q.
// Fusions (exact):
//   M0 = RY_L(q) * RZ_{L-1}(124+q)   (RZ124 commutes past the diagonal CRZ block)
//   M1 = RX(44+q) * RY(36+q)
//   M2 = RZ(88+q) * RX(80+q)         (RZ dropped in final layer)
//   CRZ block (constant angles 96..123) = one compile-time 256-entry phase table
//   Final layer: all trailing diagonals dropped (don't change probabilities).

namespace {

constexpr int NSAMP  = 4096;
constexpr int NW_L   = 132;

// ---------- compile-time trig ----------
constexpr double PI_D   = 3.14159265358979323846264338327950288;
constexpr double TWO_PI = 6.28318530717958647692528676655900577;

constexpr double red_pm_pi(double x) {
  double k = x / TWO_PI;
  long long ki = (long long)k;          // trunc toward 0
  double r = x - (double)ki * TWO_PI;
  if (r > PI_D)  r -= TWO_PI;
  if (r < -PI_D) r += TWO_PI;
  return r;
}
constexpr double csin(double x) {
  double r = red_pm_pi(x), r2 = r * r, term = r, sum = r;
  for (int n = 1; n <= 13; ++n) { term *= -r2 / (double)((2*n)*(2*n+1)); sum += term; }
  return sum;
}
constexpr double ccos(double x) {
  double r = red_pm_pi(x), r2 = r * r, term = 1.0, sum = 1.0;
  for (int n = 1; n <= 13; ++n) { term *= -r2 / (double)((2*n-1)*(2*n)); sum += term; }
  return sum;
}

// PAIRS: (j, j+gap), gap=1..7 ; control < target always
constexpr int PC[28] = {0,1,2,3,4,5,6, 0,1,2,3,4,5, 0,1,2,3,4, 0,1,2,3, 0,1,2, 0,1, 0};
constexpr int PT[28] = {1,2,3,4,5,6,7, 2,3,4,5,6,7, 3,4,5,6,7, 4,5,6,7, 5,6,7, 6,7, 7};

struct Tbl28 { float c[28]; float s[28]; };
constexpr Tbl28 mk_tbl(int base) {
  Tbl28 t{};
  for (int i = 0; i < 28; ++i) {
    double a = 0.5 * (double)(base + i);
    t.c[i] = (float)ccos(a);
    t.s[i] = (float)csin(a);
  }
  return t;
}
constexpr Tbl28 T_CRY = mk_tbl(8);    // CRY angles 8..35
constexpr Tbl28 T_CRX = mk_tbl(52);   // CRX angles 52..79

// CRZ block (angles 96..123, identical every layer) as one diagonal phase table:
// multiplier(s) = exp(i*psi(s)), psi(s) = sum_i ctrl_i(s) * (bt_i(s)? +a_i/2 : -a_i/2)
struct DTbl { float v[512]; };   // [2s]=cos, [2s+1]=sin
constexpr DTbl mk_dcrz() {
  DTbl t{};
  for (int s = 0; s < 256; ++s) {
    double psi = 0.0;
    for (int i = 0; i < 28; ++i) {
      const int pc = 7 - PC[i], pt = 7 - PT[i];
      if ((s >> pc) & 1) {
        const double half = 0.5 * (double)(96 + i);
        psi += ((s >> pt) & 1) ? half : -half;
      }
    }
    t.v[2*s]   = (float)ccos(psi);
    t.v[2*s+1] = (float)csin(psi);
  }
  return t;
}
__device__ constexpr DTbl D_CRZ = mk_dcrz();

// ---------- gate appliers ----------
// General SU(2) gate, m11=conj(m00), m10=-conj(m01). Cross-lane (bit p>=2, sh=p-2).
__device__ __forceinline__ void gen_cross(float* ar, float* ai, int lane, int sh,
                                          float m00r, float m00i, float m01r, float m01i) {
  const int lm = 1 << sh;
  const int bbit = (lane >> sh) & 1;
  const float dr = m00r;
  const float di = bbit ? -m00i : m00i;
  const float g  = bbit ? -m01r : m01r;
  const float h  = m01i;
#pragma unroll
  for (int r = 0; r < 4; ++r) {
    float pr = __shfl_xor(ar[r], lm, 64);
    float pi = __shfl_xor(ai[r], lm, 64);
    float mr = ar[r], mi = ai[r];
    ar[r] = dr*mr - di*mi + g*pr - h*pi;
    ai[r] = dr*mi + di*mr + g*pi + h*pr;
  }
}
// General SU(2), lane-local (bit p<2).
__device__ __forceinline__ void gen_local(float* ar, float* ai, int p,
                                          float m00r, float m00i, float m01r, float m01i) {
  const int m = 1 << p;
#pragma unroll
  for (int r0 = 0; r0 < 4; ++r0) {
    if (!(r0 & m)) {
      const int r1 = r0 | m;
      float a0r=ar[r0], a0i=ai[r0], a1r=ar[r1], a1i=ai[r1];
      ar[r0] =  m00r*a0r - m00i*a0i + m01r*a1r - m01i*a1i;
      ai[r0] =  m00r*a0i + m00i*a0r + m01r*a1i + m01i*a1r;
      ar[r1] = -m01r*a0r - m01i*a0i + m00r*a1r + m00i*a1i;
      ai[r1] = -m01r*a0i + m01i*a0r + m00r*a1i - m00i*a1r;
    }
  }
}

// CRY, target cross-lane (t<=5), control is lane bit (c<t<=5).
__device__ __forceinline__ void cry_cross(float* ar, float* ai, int lane,
                                          int shc, int sht, float cc, float sc) {
  const int lm = 1 << sht;
  const int ctrl = (lane >> shc) & 1;
  const float ce = ctrl ? cc : 1.0f;
  float se = ((lane >> sht) & 1) ? sc : -sc;
  se = ctrl ? se : 0.0f;
#pragma unroll
  for (int r = 0; r < 4; ++r) {
    float pr = __shfl_xor(ar[r], lm, 64);
    float pi = __shfl_xor(ai[r], lm, 64);
    ar[r] = ce*ar[r] + se*pr;
    ai[r] = ce*ai[r] + se*pi;
  }
}
// CRY, target local (t in {6,7}), control lane bit (c<=5).
__device__ __forceinline__ void cry_local(float* ar, float* ai, int lane,
                                          int shc, int pt, float cc, float sc) {
  const int ctrl = (lane >> shc) & 1;
  const float ce = ctrl ? cc : 1.0f;
  const float se = ctrl ? sc : 0.0f;
  const int m = 1 << pt;
#pragma unroll
  for (int r0 = 0; r0 < 4; ++r0) {
    if (!(r0 & m)) {
      const int r1 = r0 | m;
      float a0r=ar[r0], a0i=ai[r0], a1r=ar[r1], a1i=ai[r1];
      ar[r0] = ce*a0r - se*a1r;  ai[r0] = ce*a0i - se*a1i;
      ar[r1] = ce*a1r + se*a0r;  ai[r1] = ce*a1i + se*a0i;
    }
  }
}
// Pair (6,7): control bit = r-bit1 -> apply only to (a2,a3), unconditional.
__device__ __forceinline__ void ry_pair23(float* ar, float* ai, float cc, float sc) {
  float a0r=ar[2], a0i=ai[2], a1r=ar[3], a1i=ai[3];
  ar[2] = cc*a0r - sc*a1r;  ai[2] = cc*a0i - sc*a1i;
  ar[3] = cc*a1r + sc*a0r;  ai[3] = cc*a1i + sc*a0i;
}

// CRX variants (M = [[c,-is],[-is,c]] on target).
__device__ __forceinline__ void crx_cross(float* ar, float* ai, int lane,
                                          int shc, int sht, float cc, float sc) {
  const int lm = 1 << sht;
  const int ctrl = (lane >> shc) & 1;
  const float ce = ctrl ? cc : 1.0f;
  const float se = ctrl ? sc : 0.0f;
#pragma unroll
  for (int r = 0; r < 4; ++r) {
    float pr = __shfl_xor(ar[r], lm, 64);
    float pi = __shfl_xor(ai[r], lm, 64);
    ar[r] = ce*ar[r] + se*pi;
    ai[r] = ce*ai[r] - se*pr;
  }
}
__device__ __forceinline__ void crx_local(float* ar, float* ai, int lane,
                                          int shc, int pt, float cc, float sc) {
  const int ctrl = (lane >> shc) & 1;
  const float ce = ctrl ? cc : 1.0f;
  const float se = ctrl ? sc : 0.0f;
  const int m = 1 << pt;
#pragma unroll
  for (int r0 = 0; r0 < 4; ++r0) {
    if (!(r0 & m)) {
      const int r1 = r0 | m;
      float a0r=ar[r0], a0i=ai[r0], a1r=ar[r1], a1i=ai[r1];
      ar[r0] = ce*a0r + se*a1i;  ai[r0] = ce*a0i - se*a1r;
      ar[r1] = ce*a1r + se*a0i;  ai[r1] = ce*a1i - se*a0r;
    }
  }
}
__device__ __forceinline__ void rx_pair23(float* ar, float* ai, float cc, float sc) {
  float a0r=ar[2], a0i=ai[2], a1r=ar[3], a1i=ai[3];
  ar[2] = cc*a0r + sc*a1i;  ai[2] = cc*a0i - sc*a1r;
  ar[3] = cc*a1r + sc*a0i;  ai[3] = cc*a1i - sc*a0r;
}

} // namespace

__global__ __launch_bounds__(256) void qugcn_sim(const float* __restrict__ x,
                                                 const float* __restrict__ qw,
                                                 const float* __restrict__ fcw,
                                                 const float* __restrict__ fcb,
                                                 float* __restrict__ out) {
  __shared__ float4 sM[96];   // [layer][block j][wire q] -> (m00r, m00i, m01r, m01i)
  const int tid  = threadIdx.x;
  const int lane = tid & 63;
  const int wid  = tid >> 6;
  const int b    = blockIdx.x * 4 + wid;

  // ---- precompute fused per-wire matrices (wave-uniform, once per block) ----
  if (tid < 96) {
    const int l   = tid / 24;
    const int rem = tid - l * 24;
    const int j   = rem >> 3;
    const int q   = rem & 7;
    float a, bb;
    if (j == 0) {        // M0 = RY(qw[l][q]) * RZ(qw[l-1][124+q])
      a  = qw[l * NW_L + q];
      bb = (l > 0) ? qw[(l - 1) * NW_L + 124 + q] : 0.f;
    } else if (j == 1) { // M1 = RX(qw[l][44+q]) * RY(qw[l][36+q])
      a  = qw[l * NW_L + 44 + q];
      bb = qw[l * NW_L + 36 + q];
    } else {             // M2 = RZ(qw[l][88+q]) * RX(qw[l][80+q]); RZ dropped at l=3
      a  = (l < 3) ? qw[l * NW_L + 88 + q] : 0.f;
      bb = qw[l * NW_L + 80 + q];
    }
    float sa, ca, sb, cb;
    __sincosf(0.5f * a,  &sa, &ca);
    __sincosf(0.5f * bb, &sb, &cb);
    float4 m;
    if (j == 0)      m = make_float4(ca*cb, -ca*sb, -sa*cb, -sa*sb); // RY*RZ
    else if (j == 1) m = make_float4(ca*cb, -sa*sb, -ca*sb, -sa*cb); // RX*RY
    else             m = make_float4(ca*cb, -sa*cb, -sb*sa, -sb*ca); // RZ*RX
    sM[tid] = m;
  }

  // ---- load column b, L2-normalize ----
  float ar[4], ai[4];
#pragma unroll
  for (int r = 0; r < 4; ++r) {
    ar[r] = x[(size_t)((lane << 2) | r) * NSAMP + b];
    ai[r] = 0.f;
  }
  float ss = ar[0]*ar[0] + ar[1]*ar[1] + ar[2]*ar[2] + ar[3]*ar[3];
#pragma unroll
  for (int off = 32; off; off >>= 1) ss += __shfl_xor(ss, off, 64);
  const float rn = 1.0f / sqrtf(ss);
#pragma unroll
  for (int r = 0; r < 4; ++r) ar[r] *= rn;

  // ---- preload this lane's 4 entries of the CRZ diagonal ----
  float dzr[4], dzi[4];
#pragma unroll
  for (int r = 0; r < 4; ++r) {
    const int s = (lane << 2) | r;
    dzr[r] = D_CRZ.v[2*s];
    dzi[r] = D_CRZ.v[2*s+1];
  }

  __syncthreads();

  // ---- 4 layers ----
#pragma unroll 1
  for (int l = 0; l < 4; ++l) {
    const int base = l * 24;

    // M0 block
#pragma unroll
    for (int q = 0; q < 8; ++q) {
      float4 m = sM[base + q];
      if (q <= 5) gen_cross(ar, ai, lane, 5 - q, m.x, m.y, m.z, m.w);
      else        gen_local(ar, ai, 7 - q, m.x, m.y, m.z, m.w);
    }
    // CRY block (constant angles)
#pragma unroll
    for (int i = 0; i < 28; ++i) {
      const int c = PC[i], t = PT[i];
      const float cc = T_CRY.c[i], sc = T_CRY.s[i];
      if (t <= 5)      cry_cross(ar, ai, lane, 5 - c, 5 - t, cc, sc);
      else if (c <= 5) cry_local(ar, ai, lane, 5 - c, 7 - t, cc, sc);
      else             ry_pair23(ar, ai, cc, sc);
    }
    // M1 block
#pragma unroll
    for (int q = 0; q < 8; ++q) {
      float4 m = sM[base + 8 + q];
      if (q <= 5) gen_cross(ar, ai, lane, 5 - q, m.x, m.y, m.z, m.w);
      else        gen_local(ar, ai, 7 - q, m.x, m.y, m.z, m.w);
    }
    // CRX block (constant angles)
#pragma unroll
    for (int i = 0; i < 28; ++i) {
      const int c = PC[i], t = PT[i];
      const float cc = T_CRX.c[i], sc = T_CRX.s[i];
      if (t <= 5)      crx_cross(ar, ai, lane, 5 - c, 5 - t, cc, sc);
      else if (c <= 5) crx_local(ar, ai, lane, 5 - c, 7 - t, cc, sc);
      else             rx_pair23(ar, ai, cc, sc);
    }
    // M2 block
#pragma unroll
    for (int q = 0; q < 8; ++q) {
      float4 m = sM[base + 16 + q];
      if (q <= 5) gen_cross(ar, ai, lane, 5 - q, m.x, m.y, m.z, m.w);
      else        gen_local(ar, ai, 7 - q, m.x, m.y, m.z, m.w);
    }
    // CRZ diagonal (skipped on final layer: doesn't affect probabilities)
    if (l < 3) {
#pragma unroll
      for (int r = 0; r < 4; ++r) {
        float mr = ar[r], mi = ai[r];
        ar[r] = mr*dzr[r] - mi*dzi[r];
        ai[r] = mr*dzi[r] + mi*dzr[r];
      }
    }
  }

  // ---- probabilities and <Z_q> ----
  float p4[4];
#pragma unroll
  for (int r = 0; r < 4; ++r) p4[r] = ar[r]*ar[r] + ai[r]*ai[r];

  float z[8];
#pragma unroll
  for (int q = 0; q < 8; ++q) {
    const int pbit = 7 - q;
    float acc = 0.f;
#pragma unroll
    for (int r = 0; r < 4; ++r) {
      const int bit = (pbit >= 2) ? ((lane >> (pbit - 2)) & 1) : ((r >> pbit) & 1);
      acc += bit ? -p4[r] : p4[r];
    }
#pragma unroll
    for (int off = 32; off; off >>= 1) acc += __shfl_xor(acc, off, 64);
    z[q] = acc;
  }

  // ---- linear head ----
  if (lane < 7) {
    float o = fcb[lane];
#pragma unroll
    for (int q = 0; q < 8; ++q) o = fmaf(fcw[lane * 8 + q], z[q], o);
    out[(size_t)b * 7 + lane] = o;
  }
}

extern "C" void kernel_launch(void* const* d_in, const int* in_sizes, int n_in,
                              void* d_out, int out_size, void* d_ws, size_t ws_size,
                              hipStream_t stream) {
  const float* x   = (const float*)d_in[0];   // [256, 4096]
  const float* qw  = (const float*)d_in[1];   // [4, 132]
  const float* fcw = (const float*)d_in[2];   // [7, 8]
  const float* fcb = (const float*)d_in[3];   // [7]
  float* out = (float*)d_out;                 // [4096, 7]
  hipLaunchKernelGGL(qugcn_sim, dim3(NSAMP / 4), dim3(256), 0, stream,
                     x, qw, fcw, fcb, out);
}

// Round 3
// 149.198 us; speedup vs baseline: 1.3349x; 1.3349x over previous
//
#include <hip/hip_runtime.h>
#include <math.h>

// QuGCN restructured: the circuit is a fixed 256x256 complex unitary U.
// Kernel A: build U^T by simulating the 256 basis states (verified R2 engine).
// Kernel B: amps = U x  (two real fp32 GEMMs, U complex x real input),
//           fused epilogue |amp|^2 -> <Z_q> -> normalize -> linear head.

namespace {

constexpr int NSAMP  = 4096;
constexpr int NW_L   = 132;

// ---------- compile-time trig ----------
constexpr double PI_D   = 3.14159265358979323846264338327950288;
constexpr double TWO_PI = 6.28318530717958647692528676655900577;

constexpr double red_pm_pi(double x) {
  double k = x / TWO_PI;
  long long ki = (long long)k;
  double r = x - (double)ki * TWO_PI;
  if (r > PI_D)  r -= TWO_PI;
  if (r < -PI_D) r += TWO_PI;
  return r;
}
constexpr double csin(double x) {
  double r = red_pm_pi(x), r2 = r * r, term = r, sum = r;
  for (int n = 1; n <= 13; ++n) { term *= -r2 / (double)((2*n)*(2*n+1)); sum += term; }
  return sum;
}
constexpr double ccos(double x) {
  double r = red_pm_pi(x), r2 = r * r, term = 1.0, sum = 1.0;
  for (int n = 1; n <= 13; ++n) { term *= -r2 / (double)((2*n-1)*(2*n)); sum += term; }
  return sum;
}

// PAIRS: (j, j+gap), gap=1..7 ; control < target always
constexpr int PC[28] = {0,1,2,3,4,5,6, 0,1,2,3,4,5, 0,1,2,3,4, 0,1,2,3, 0,1,2, 0,1, 0};
constexpr int PT[28] = {1,2,3,4,5,6,7, 2,3,4,5,6,7, 3,4,5,6,7, 4,5,6,7, 5,6,7, 6,7, 7};

struct Tbl28 { float c[28]; float s[28]; };
constexpr Tbl28 mk_tbl(int base) {
  Tbl28 t{};
  for (int i = 0; i < 28; ++i) {
    double a = 0.5 * (double)(base + i);
    t.c[i] = (float)ccos(a);
    t.s[i] = (float)csin(a);
  }
  return t;
}
constexpr Tbl28 T_CRY = mk_tbl(8);    // CRY angles 8..35
constexpr Tbl28 T_CRX = mk_tbl(52);   // CRX angles 52..79

// CRZ block (constant angles 96..123) as one diagonal phase table.
struct DTbl { float v[512]; };
constexpr DTbl mk_dcrz() {
  DTbl t{};
  for (int s = 0; s < 256; ++s) {
    double psi = 0.0;
    for (int i = 0; i < 28; ++i) {
      const int pc = 7 - PC[i], pt = 7 - PT[i];
      if ((s >> pc) & 1) {
        const double half = 0.5 * (double)(96 + i);
        psi += ((s >> pt) & 1) ? half : -half;
      }
    }
    t.v[2*s]   = (float)ccos(psi);
    t.v[2*s+1] = (float)csin(psi);
  }
  return t;
}
__device__ constexpr DTbl D_CRZ = mk_dcrz();

// ---------- gate appliers (verified in R2) ----------
__device__ __forceinline__ void gen_cross(float* ar, float* ai, int lane, int sh,
                                          float m00r, float m00i, float m01r, float m01i) {
  const int lm = 1 << sh;
  const int bbit = (lane >> sh) & 1;
  const float dr = m00r;
  const float di = bbit ? -m00i : m00i;
  const float g  = bbit ? -m01r : m01r;
  const float h  = m01i;
#pragma unroll
  for (int r = 0; r < 4; ++r) {
    float pr = __shfl_xor(ar[r], lm, 64);
    float pi = __shfl_xor(ai[r], lm, 64);
    float mr = ar[r], mi = ai[r];
    ar[r] = dr*mr - di*mi + g*pr - h*pi;
    ai[r] = dr*mi + di*mr + g*pi + h*pr;
  }
}
__device__ __forceinline__ void gen_local(float* ar, float* ai, int p,
                                          float m00r, float m00i, float m01r, float m01i) {
  const int m = 1 << p;
#pragma unroll
  for (int r0 = 0; r0 < 4; ++r0) {
    if (!(r0 & m)) {
      const int r1 = r0 | m;
      float a0r=ar[r0], a0i=ai[r0], a1r=ar[r1], a1i=ai[r1];
      ar[r0] =  m00r*a0r - m00i*a0i + m01r*a1r - m01i*a1i;
      ai[r0] =  m00r*a0i + m00i*a0r + m01r*a1i + m01i*a1r;
      ar[r1] = -m01r*a0r - m01i*a0i + m00r*a1r + m00i*a1i;
      ai[r1] = -m01r*a0i + m01i*a0r + m00r*a1i - m00i*a1r;
    }
  }
}
__device__ __forceinline__ void cry_cross(float* ar, float* ai, int lane,
                                          int shc, int sht, float cc, float sc) {
  const int lm = 1 << sht;
  const int ctrl = (lane >> shc) & 1;
  const float ce = ctrl ? cc : 1.0f;
  float se = ((lane >> sht) & 1) ? sc : -sc;
  se = ctrl ? se : 0.0f;
#pragma unroll
  for (int r = 0; r < 4; ++r) {
    float pr = __shfl_xor(ar[r], lm, 64);
    float pi = __shfl_xor(ai[r], lm, 64);
    ar[r] = ce*ar[r] + se*pr;
    ai[r] = ce*ai[r] + se*pi;
  }
}
__device__ __forceinline__ void cry_local(float* ar, float* ai, int lane,
                                          int shc, int pt, float cc, float sc) {
  const int ctrl = (lane >> shc) & 1;
  const float ce = ctrl ? cc : 1.0f;
  const float se = ctrl ? sc : 0.0f;
  const int m = 1 << pt;
#pragma unroll
  for (int r0 = 0; r0 < 4; ++r0) {
    if (!(r0 & m)) {
      const int r1 = r0 | m;
      float a0r=ar[r0], a0i=ai[r0], a1r=ar[r1], a1i=ai[r1];
      ar[r0] = ce*a0r - se*a1r;  ai[r0] = ce*a0i - se*a1i;
      ar[r1] = ce*a1r + se*a0r;  ai[r1] = ce*a1i + se*a0i;
    }
  }
}
__device__ __forceinline__ void ry_pair23(float* ar, float* ai, float cc, float sc) {
  float a0r=ar[2], a0i=ai[2], a1r=ar[3], a1i=ai[3];
  ar[2] = cc*a0r - sc*a1r;  ai[2] = cc*a0i - sc*a1i;
  ar[3] = cc*a1r + sc*a0r;  ai[3] = cc*a1i + sc*a0i;
}
__device__ __forceinline__ void crx_cross(float* ar, float* ai, int lane,
                                          int shc, int sht, float cc, float sc) {
  const int lm = 1 << sht;
  const int ctrl = (lane >> shc) & 1;
  const float ce = ctrl ? cc : 1.0f;
  const float se = ctrl ? sc : 0.0f;
#pragma unroll
  for (int r = 0; r < 4; ++r) {
    float pr = __shfl_xor(ar[r], lm, 64);
    float pi = __shfl_xor(ai[r], lm, 64);
    ar[r] = ce*ar[r] + se*pi;
    ai[r] = ce*ai[r] - se*pr;
  }
}
__device__ __forceinline__ void crx_local(float* ar, float* ai, int lane,
                                          int shc, int pt, float cc, float sc) {
  const int ctrl = (lane >> shc) & 1;
  const float ce = ctrl ? cc : 1.0f;
  const float se = ctrl ? sc : 0.0f;
  const int m = 1 << pt;
#pragma unroll
  for (int r0 = 0; r0 < 4; ++r0) {
    if (!(r0 & m)) {
      const int r1 = r0 | m;
      float a0r=ar[r0], a0i=ai[r0], a1r=ar[r1], a1i=ai[r1];
      ar[r0] = ce*a0r + se*a1i;  ai[r0] = ce*a0i - se*a1r;
      ar[r1] = ce*a1r + se*a0i;  ai[r1] = ce*a1i - se*a0r;
    }
  }
}
__device__ __forceinline__ void rx_pair23(float* ar, float* ai, float cc, float sc) {
  float a0r=ar[2], a0i=ai[2], a1r=ar[3], a1i=ai[3];
  ar[2] = cc*a0r + sc*a1i;  ai[2] = cc*a0i - sc*a1r;
  ar[3] = cc*a1r + sc*a0i;  ai[3] = cc*a1i - sc*a0r;
}

} // namespace

// ---------------- Kernel A: build U^T ----------------
// wave w simulates basis state e_w; final amps = column w of U.
// Stores Ure[w][o], Uim[w][o] (row-major 256 floats per row).
__global__ __launch_bounds__(256) void build_u(const float* __restrict__ qw,
                                               float* __restrict__ Ure,
                                               float* __restrict__ Uim) {
  __shared__ float4 sM[96];
  const int tid  = threadIdx.x;
  const int lane = tid & 63;
  const int wid  = tid >> 6;
  const int s0   = blockIdx.x * 4 + wid;   // basis index, 0..255

  // fused per-wire matrices (verified R2)
  if (tid < 96) {
    const int l   = tid / 24;
    const int rem = tid - l * 24;
    const int j   = rem >> 3;
    const int q   = rem & 7;
    float a, bb;
    if (j == 0) {        // M0 = RY(qw[l][q]) * RZ(qw[l-1][124+q])
      a  = qw[l * NW_L + q];
      bb = (l > 0) ? qw[(l - 1) * NW_L + 124 + q] : 0.f;
    } else if (j == 1) { // M1 = RX(qw[l][44+q]) * RY(qw[l][36+q])
      a  = qw[l * NW_L + 44 + q];
      bb = qw[l * NW_L + 36 + q];
    } else {             // M2 = RZ(qw[l][88+q]) * RX(qw[l][80+q]); RZ dropped at l=3
      a  = (l < 3) ? qw[l * NW_L + 88 + q] : 0.f;
      bb = qw[l * NW_L + 80 + q];
    }
    float sa, ca, sb, cb;
    __sincosf(0.5f * a,  &sa, &ca);
    __sincosf(0.5f * bb, &sb, &cb);
    float4 m;
    if (j == 0)      m = make_float4(ca*cb, -ca*sb, -sa*cb, -sa*sb); // RY*RZ
    else if (j == 1) m = make_float4(ca*cb, -sa*sb, -ca*sb, -sa*cb); // RX*RY
    else             m = make_float4(ca*cb, -sa*cb, -sb*sa, -sb*ca); // RZ*RX
    sM[tid] = m;
  }

  // basis state
  float ar[4], ai[4];
#pragma unroll
  for (int r = 0; r < 4; ++r) {
    ar[r] = (((lane << 2) | r) == s0) ? 1.f : 0.f;
    ai[r] = 0.f;
  }

  // CRZ diagonal entries for this lane
  float dzr[4], dzi[4];
#pragma unroll
  for (int r = 0; r < 4; ++r) {
    const int s = (lane << 2) | r;
    dzr[r] = D_CRZ.v[2*s];
    dzi[r] = D_CRZ.v[2*s+1];
  }

  __syncthreads();

#pragma unroll 1
  for (int l = 0; l < 4; ++l) {
    const int base = l * 24;
#pragma unroll
    for (int q = 0; q < 8; ++q) {
      float4 m = sM[base + q];
      if (q <= 5) gen_cross(ar, ai, lane, 5 - q, m.x, m.y, m.z, m.w);
      else        gen_local(ar, ai, 7 - q, m.x, m.y, m.z, m.w);
    }
#pragma unroll
    for (int i = 0; i < 28; ++i) {
      const int c = PC[i], t = PT[i];
      const float cc = T_CRY.c[i], sc = T_CRY.s[i];
      if (t <= 5)      cry_cross(ar, ai, lane, 5 - c, 5 - t, cc, sc);
      else if (c <= 5) cry_local(ar, ai, lane, 5 - c, 7 - t, cc, sc);
      else             ry_pair23(ar, ai, cc, sc);
    }
#pragma unroll
    for (int q = 0; q < 8; ++q) {
      float4 m = sM[base + 8 + q];
      if (q <= 5) gen_cross(ar, ai, lane, 5 - q, m.x, m.y, m.z, m.w);
      else        gen_local(ar, ai, 7 - q, m.x, m.y, m.z, m.w);
    }
#pragma unroll
    for (int i = 0; i < 28; ++i) {
      const int c = PC[i], t = PT[i];
      const float cc = T_CRX.c[i], sc = T_CRX.s[i];
      if (t <= 5)      crx_cross(ar, ai, lane, 5 - c, 5 - t, cc, sc);
      else if (c <= 5) crx_local(ar, ai, lane, 5 - c, 7 - t, cc, sc);
      else             rx_pair23(ar, ai, cc, sc);
    }
#pragma unroll
    for (int q = 0; q < 8; ++q) {
      float4 m = sM[base + 16 + q];
      if (q <= 5) gen_cross(ar, ai, lane, 5 - q, m.x, m.y, m.z, m.w);
      else        gen_local(ar, ai, 7 - q, m.x, m.y, m.z, m.w);
    }
    if (l < 3) {
#pragma unroll
      for (int r = 0; r < 4; ++r) {
        float mr = ar[r], mi = ai[r];
        ar[r] = mr*dzr[r] - mi*dzi[r];
        ai[r] = mr*dzi[r] + mi*dzr[r];
      }
    }
  }

  // store row s0 of U^T: amp o lives at lane (o>>2), reg (o&3) -> float4 per lane
  float4 re4 = make_float4(ar[0], ar[1], ar[2], ar[3]);
  float4 im4 = make_float4(ai[0], ai[1], ai[2], ai[3]);
  ((float4*)(Ure + (size_t)s0 * 256))[lane] = re4;
  ((float4*)(Uim + (size_t)s0 * 256))[lane] = im4;
}

// ---------------- Kernel B: GEMM + epilogue ----------------
// Block: 16 cols x 512 "rows" (256 re + 256 im). 256 threads:
//   tg = tid&3 (4 col-groups of 4), to = tid>>2 (64 o-groups of 8).
// acc[j*4+cc] = amp(o = to*8+j, col = tg*4+cc). K=256 staged in 16-k tiles.
__global__ __launch_bounds__(256) void gemm_eval(const float* __restrict__ x,
                                                 const float* __restrict__ Ure,
                                                 const float* __restrict__ Uim,
                                                 const float* __restrict__ fcw,
                                                 const float* __restrict__ fcb,
                                                 float* __restrict__ out) {
  __shared__ __align__(16) char smem[65536];
  float* Xs = (float*)smem;               // [k 256][col 16] = 16 KB
  float* Us = (float*)(smem + 16384);     // [kk 16][chunk 64 * 12] = 48 KB (swizzled)
  const int tid = threadIdx.x;
  const int tg  = tid & 3;
  const int to  = tid >> 2;
  const int colbase = blockIdx.x * 16;

  // stage X tile (coalesced; x is [256][4096] row-major)
#pragma unroll
  for (int i = 0; i < 16; ++i) {
    const int f = i * 256 + tid;
    const int k = f >> 4, c = f & 15;
    Xs[f] = x[(size_t)k * NSAMP + colbase + c];
  }
  float acc[32];
#pragma unroll
  for (int i = 0; i < 32; ++i) acc[i] = 0.f;
  __syncthreads();

#pragma unroll 1
  for (int kt = 0; kt < 16; ++kt) {
    __syncthreads();   // previous k-tile fully consumed
    // stage Us: rows s = kt*16+kk ; chunk cidx (8 floats) stored at cidx*12 (2-way banks)
#pragma unroll
    for (int i = 0; i < 8; ++i) {
      const int slot = i * 256 + tid;      // 2048 float4 slots
      const int kk = slot >> 7;
      const int f4 = slot & 127;
      const int o  = f4 << 2;
      const int s  = kt * 16 + kk;
      const float* src = (o < 256) ? (Ure + (size_t)s * 256 + o)
                                   : (Uim + (size_t)s * 256 + (o - 256));
      const float4 v = *(const float4*)src;
      *(float4*)&Us[kk * 768 + (f4 >> 1) * 12 + (f4 & 1) * 4] = v;
    }
    __syncthreads();
#pragma unroll
    for (int kk = 0; kk < 16; ++kk) {
      const float4 xv = *(const float4*)&Xs[(kt * 16 + kk) * 16 + tg * 4];
      const float4 u0 = *(const float4*)&Us[kk * 768 + to * 12];
      const float4 u1 = *(const float4*)&Us[kk * 768 + to * 12 + 4];
      const float uj[8] = {u0.x, u0.y, u0.z, u0.w, u1.x, u1.y, u1.z, u1.w};
#pragma unroll
      for (int j = 0; j < 8; ++j) {
        acc[j*4+0] = fmaf(uj[j], xv.x, acc[j*4+0]);
        acc[j*4+1] = fmaf(uj[j], xv.y, acc[j*4+1]);
        acc[j*4+2] = fmaf(uj[j], xv.z, acc[j*4+2]);
        acc[j*4+3] = fmaf(uj[j], xv.w, acc[j*4+3]);
      }
    }
  }
  __syncthreads();

  // ---- epilogue: per-thread signed partial sums of |amp|^2 ----
  // s = (to&31)*8 + j  (same mapping for re (to<32) and im (to>=32)).
  // z_q = sum_s sign_q(s) p_s ; q<=4 sign from to-bits, q>=5 sign from j-bits.
  float* Ps = (float*)smem;   // [to 64][col 16][4: zsum,z5,z6,z7] = 16 KB
#pragma unroll
  for (int cc = 0; cc < 4; ++cc) {
    float sq[8];
#pragma unroll
    for (int j = 0; j < 8; ++j) { const float a = acc[j*4+cc]; sq[j] = a * a; }
    const float s03 = sq[0]+sq[1]+sq[2]+sq[3], s47 = sq[4]+sq[5]+sq[6]+sq[7];
    const float zsum = s03 + s47;
    const float z5 = s03 - s47;                                  // s bit2 = j bit2
    const float z6 = (sq[0]+sq[1]-sq[2]-sq[3]) + (sq[4]+sq[5]-sq[6]-sq[7]); // j bit1
    const float z7 = (sq[0]-sq[1]+sq[2]-sq[3]) + (sq[4]-sq[5]+sq[6]-sq[7]); // j bit0
    const int c = tg * 4 + cc;
    *(float4*)&Ps[(to * 16 + c) * 4] = make_float4(zsum, z5, z6, z7);
  }
  __syncthreads();

  float* Zs = (float*)(smem + 16384);   // [col 16][9: z0..z7, zsum]
  if (tid < 144) {
    const int col = tid / 9, q = tid - col * 9;
    float z = 0.f;
    for (int t = 0; t < 64; ++t) {
      const float* p = &Ps[(t * 16 + col) * 4];
      if (q <= 4) {
        const int sgn = ((t & 31) >> (4 - q)) & 1;   // s>>(7-q) = bit (4-q) of (to&31)
        z += sgn ? -p[0] : p[0];
      } else if (q < 8) {
        z += p[q - 4];
      } else {
        z += p[0];
      }
    }
    Zs[col * 9 + q] = z;
  }
  __syncthreads();

  if (tid < 112) {
    const int col = tid / 7, oo = tid - col * 7;
    const float inv = 1.0f / Zs[col * 9 + 8];
    float v = fcb[oo];
#pragma unroll
    for (int q = 0; q < 8; ++q)
      v = fmaf(fcw[oo * 8 + q], Zs[col * 9 + q] * inv, v);
    out[(size_t)(colbase + col) * 7 + oo] = v;
  }
}

extern "C" void kernel_launch(void* const* d_in, const int* in_sizes, int n_in,
                              void* d_out, int out_size, void* d_ws, size_t ws_size,
                              hipStream_t stream) {
  const float* x   = (const float*)d_in[0];   // [256, 4096]
  const float* qw  = (const float*)d_in[1];   // [4, 132]
  const float* fcw = (const float*)d_in[2];   // [7, 8]
  const float* fcb = (const float*)d_in[3];   // [7]
  float* out = (float*)d_out;                 // [4096, 7]

  float* Ure = (float*)d_ws;                  // 256*256 fp32
  float* Uim = Ure + 256 * 256;               // 256*256 fp32 (512 KB total)

  hipLaunchKernelGGL(build_u,   dim3(64),  dim3(256), 0, stream, qw, Ure, Uim);
  hipLaunchKernelGGL(gemm_eval, dim3(256), dim3(256), 0, stream, x, Ure, Uim,
                     fcw, fcb, out);
}

// Round 4
// 98.751 us; speedup vs baseline: 2.0168x; 1.5109x over previous
//
#include <hip/hip_runtime.h>
#include <math.h>

// QuGCN pipeline v3:
//   K1 build_half : 512 waves simulate 256 basis states through each half of the
//                   circuit (U = U2*U1, split between layers 1 and 2; exact).
//   K2 combine_u  : U = U2*U1 complex GEMM (fp32), emits U as bf16 [re;im] rows.
//   K3 mfma_eval  : amps = U*x via mfma_f32_16x16x32_bf16 (fp32 accum), fused
//                   |amp|^2 -> <Z_q> -> normalize -> linear head.

namespace {

constexpr int NSAMP = 4096;
constexpr int NW_L  = 132;

// ---------- compile-time trig ----------
constexpr double PI_D   = 3.14159265358979323846264338327950288;
constexpr double TWO_PI = 6.28318530717958647692528676655900577;

constexpr double red_pm_pi(double x) {
  double k = x / TWO_PI;
  long long ki = (long long)k;
  double r = x - (double)ki * TWO_PI;
  if (r > PI_D)  r -= TWO_PI;
  if (r < -PI_D) r += TWO_PI;
  return r;
}
constexpr double csin(double x) {
  double r = red_pm_pi(x), r2 = r * r, term = r, sum = r;
  for (int n = 1; n <= 13; ++n) { term *= -r2 / (double)((2*n)*(2*n+1)); sum += term; }
  return sum;
}
constexpr double ccos(double x) {
  double r = red_pm_pi(x), r2 = r * r, term = 1.0, sum = 1.0;
  for (int n = 1; n <= 13; ++n) { term *= -r2 / (double)((2*n-1)*(2*n)); sum += term; }
  return sum;
}

constexpr int PC[28] = {0,1,2,3,4,5,6, 0,1,2,3,4,5, 0,1,2,3,4, 0,1,2,3, 0,1,2, 0,1, 0};
constexpr int PT[28] = {1,2,3,4,5,6,7, 2,3,4,5,6,7, 3,4,5,6,7, 4,5,6,7, 5,6,7, 6,7, 7};

struct Tbl28 { float c[28]; float s[28]; };
constexpr Tbl28 mk_tbl(int base) {
  Tbl28 t{};
  for (int i = 0; i < 28; ++i) {
    double a = 0.5 * (double)(base + i);
    t.c[i] = (float)ccos(a);
    t.s[i] = (float)csin(a);
  }
  return t;
}
constexpr Tbl28 T_CRY = mk_tbl(8);
constexpr Tbl28 T_CRX = mk_tbl(52);

struct DTbl { float v[512]; };
constexpr DTbl mk_dcrz() {
  DTbl t{};
  for (int s = 0; s < 256; ++s) {
    double psi = 0.0;
    for (int i = 0; i < 28; ++i) {
      const int pc = 7 - PC[i], pt = 7 - PT[i];
      if ((s >> pc) & 1) {
        const double half = 0.5 * (double)(96 + i);
        psi += ((s >> pt) & 1) ? half : -half;
      }
    }
    t.v[2*s]   = (float)ccos(psi);
    t.v[2*s+1] = (float)csin(psi);
  }
  return t;
}
__device__ constexpr DTbl D_CRZ = mk_dcrz();

// ---------- gate appliers (verified R2/R3) ----------
__device__ __forceinline__ void gen_cross(float* ar, float* ai, int lane, int sh,
                                          float m00r, float m00i, float m01r, float m01i) {
  const int lm = 1 << sh;
  const int bbit = (lane >> sh) & 1;
  const float dr = m00r;
  const float di = bbit ? -m00i : m00i;
  const float g  = bbit ? -m01r : m01r;
  const float h  = m01i;
#pragma unroll
  for (int r = 0; r < 4; ++r) {
    float pr = __shfl_xor(ar[r], lm, 64);
    float pi = __shfl_xor(ai[r], lm, 64);
    float mr = ar[r], mi = ai[r];
    ar[r] = dr*mr - di*mi + g*pr - h*pi;
    ai[r] = dr*mi + di*mr + g*pi + h*pr;
  }
}
__device__ __forceinline__ void gen_local(float* ar, float* ai, int p,
                                          float m00r, float m00i, float m01r, float m01i) {
  const int m = 1 << p;
#pragma unroll
  for (int r0 = 0; r0 < 4; ++r0) {
    if (!(r0 & m)) {
      const int r1 = r0 | m;
      float a0r=ar[r0], a0i=ai[r0], a1r=ar[r1], a1i=ai[r1];
      ar[r0] =  m00r*a0r - m00i*a0i + m01r*a1r - m01i*a1i;
      ai[r0] =  m00r*a0i + m00i*a0r + m01r*a1i + m01i*a1r;
      ar[r1] = -m01r*a0r - m01i*a0i + m00r*a1r + m00i*a1i;
      ai[r1] = -m01r*a0i + m01i*a0r + m00r*a1i - m00i*a1r;
    }
  }
}
__device__ __forceinline__ void cry_cross(float* ar, float* ai, int lane,
                                          int shc, int sht, float cc, float sc) {
  const int lm = 1 << sht;
  const int ctrl = (lane >> shc) & 1;
  const float ce = ctrl ? cc : 1.0f;
  float se = ((lane >> sht) & 1) ? sc : -sc;
  se = ctrl ? se : 0.0f;
#pragma unroll
  for (int r = 0; r < 4; ++r) {
    float pr = __shfl_xor(ar[r], lm, 64);
    float pi = __shfl_xor(ai[r], lm, 64);
    ar[r] = ce*ar[r] + se*pr;
    ai[r] = ce*ai[r] + se*pi;
  }
}
__device__ __forceinline__ void cry_local(float* ar, float* ai, int lane,
                                          int shc, int pt, float cc, float sc) {
  const int ctrl = (lane >> shc) & 1;
  const float ce = ctrl ? cc : 1.0f;
  const float se = ctrl ? sc : 0.0f;
  const int m = 1 << pt;
#pragma unroll
  for (int r0 = 0; r0 < 4; ++r0) {
    if (!(r0 & m)) {
      const int r1 = r0 | m;
      float a0r=ar[r0], a0i=ai[r0], a1r=ar[r1], a1i=ai[r1];
      ar[r0] = ce*a0r - se*a1r;  ai[r0] = ce*a0i - se*a1i;
      ar[r1] = ce*a1r + se*a0r;  ai[r1] = ce*a1i + se*a0i;
    }
  }
}
__device__ __forceinline__ void ry_pair23(float* ar, float* ai, float cc, float sc) {
  float a0r=ar[2], a0i=ai[2], a1r=ar[3], a1i=ai[3];
  ar[2] = cc*a0r - sc*a1r;  ai[2] = cc*a0i - sc*a1i;
  ar[3] = cc*a1r + sc*a0r;  ai[3] = cc*a1i + sc*a0i;
}
__device__ __forceinline__ void crx_cross(float* ar, float* ai, int lane,
                                          int shc, int sht, float cc, float sc) {
  const int lm = 1 << sht;
  const int ctrl = (lane >> shc) & 1;
  const float ce = ctrl ? cc : 1.0f;
  const float se = ctrl ? sc : 0.0f;
#pragma unroll
  for (int r = 0; r < 4; ++r) {
    float pr = __shfl_xor(ar[r], lm, 64);
    float pi = __shfl_xor(ai[r], lm, 64);
    ar[r] = ce*ar[r] + se*pi;
    ai[r] = ce*ai[r] - se*pr;
  }
}
__device__ __forceinline__ void crx_local(float* ar, float* ai, int lane,
                                          int shc, int pt, float cc, float sc) {
  const int ctrl = (lane >> shc) & 1;
  const float ce = ctrl ? cc : 1.0f;
  const float se = ctrl ? sc : 0.0f;
  const int m = 1 << pt;
#pragma unroll
  for (int r0 = 0; r0 < 4; ++r0) {
    if (!(r0 & m)) {
      const int r1 = r0 | m;
      float a0r=ar[r0], a0i=ai[r0], a1r=ar[r1], a1i=ai[r1];
      ar[r0] = ce*a0r + se*a1i;  ai[r0] = ce*a0i - se*a1r;
      ar[r1] = ce*a1r + se*a0i;  ai[r1] = ce*a1i - se*a0r;
    }
  }
}
__device__ __forceinline__ void rx_pair23(float* ar, float* ai, float cc, float sc) {
  float a0r=ar[2], a0i=ai[2], a1r=ar[3], a1i=ai[3];
  ar[2] = cc*a0r + sc*a1i;  ai[2] = cc*a0i - sc*a1r;
  ar[3] = cc*a1r + sc*a0i;  ai[3] = cc*a1i - sc*a0r;
}

// round-to-nearest-even fp32 -> bf16
__device__ __forceinline__ unsigned short f2bf(float f) {
  unsigned int u = __float_as_uint(f);
  u = (u + 0x7FFFu + ((u >> 16) & 1u)) >> 16;
  return (unsigned short)u;
}

typedef __attribute__((ext_vector_type(8))) short bf16x8;
typedef __attribute__((ext_vector_type(4))) float f32x4;

} // namespace

// ---------------- K1: build half-circuit unitaries ----------------
// block = (half h, basis s0); 1 wave. Writes Uh^T as complex pairs:
// Uhc[s0*512 + o*2] = re, +1 = im  (Uh[o][s0]).
__global__ __launch_bounds__(64) void build_half(const float* __restrict__ qw,
                                                 float* __restrict__ U1c,
                                                 float* __restrict__ U2c) {
  __shared__ float4 sM[48];
  const int lane = threadIdx.x;
  const int h    = blockIdx.x >> 8;
  const int s0   = blockIdx.x & 255;

  if (lane < 48) {
    const int lp  = lane / 24;
    const int rem = lane - lp * 24;
    const int j   = rem >> 3;
    const int q   = rem & 7;
    const int l   = 2 * h + lp;
    float a, bb;
    if (j == 0) {        // M0 = RY(qw[l][q]) * RZ(qw[l-1][124+q])
      a  = qw[l * NW_L + q];
      bb = (l > 0) ? qw[(l - 1) * NW_L + 124 + q] : 0.f;
    } else if (j == 1) { // M1 = RX(44+q) * RY(36+q)
      a  = qw[l * NW_L + 44 + q];
      bb = qw[l * NW_L + 36 + q];
    } else {             // M2 = RZ(88+q) * RX(80+q); RZ dropped at l=3
      a  = (l < 3) ? qw[l * NW_L + 88 + q] : 0.f;
      bb = qw[l * NW_L + 80 + q];
    }
    float sa, ca, sb, cb;
    __sincosf(0.5f * a,  &sa, &ca);
    __sincosf(0.5f * bb, &sb, &cb);
    float4 m;
    if (j == 0)      m = make_float4(ca*cb, -ca*sb, -sa*cb, -sa*sb); // RY*RZ
    else if (j == 1) m = make_float4(ca*cb, -sa*sb, -ca*sb, -sa*cb); // RX*RY
    else             m = make_float4(ca*cb, -sa*cb, -sb*sa, -sb*ca); // RZ*RX
    sM[lane] = m;
  }

  float ar[4], ai[4];
#pragma unroll
  for (int r = 0; r < 4; ++r) {
    ar[r] = (((lane << 2) | r) == s0) ? 1.f : 0.f;
    ai[r] = 0.f;
  }
  float dzr[4], dzi[4];
#pragma unroll
  for (int r = 0; r < 4; ++r) {
    const int s = (lane << 2) | r;
    dzr[r] = D_CRZ.v[2*s];
    dzi[r] = D_CRZ.v[2*s+1];
  }
  __syncthreads();

#pragma unroll 1
  for (int lp = 0; lp < 2; ++lp) {
    const int base = lp * 24;
#pragma unroll
    for (int q = 0; q < 8; ++q) {
      float4 m = sM[base + q];
      if (q <= 5) gen_cross(ar, ai, lane, 5 - q, m.x, m.y, m.z, m.w);
      else        gen_local(ar, ai, 7 - q, m.x, m.y, m.z, m.w);
    }
#pragma unroll
    for (int i = 0; i < 28; ++i) {
      const int c = PC[i], t = PT[i];
      const float cc = T_CRY.c[i], sc = T_CRY.s[i];
      if (t <= 5)      cry_cross(ar, ai, lane, 5 - c, 5 - t, cc, sc);
      else if (c <= 5) cry_local(ar, ai, lane, 5 - c, 7 - t, cc, sc);
      else             ry_pair23(ar, ai, cc, sc);
    }
#pragma unroll
    for (int q = 0; q < 8; ++q) {
      float4 m = sM[base + 8 + q];
      if (q <= 5) gen_cross(ar, ai, lane, 5 - q, m.x, m.y, m.z, m.w);
      else        gen_local(ar, ai, 7 - q, m.x, m.y, m.z, m.w);
    }
#pragma unroll
    for (int i = 0; i < 28; ++i) {
      const int c = PC[i], t = PT[i];
      const float cc = T_CRX.c[i], sc = T_CRX.s[i];
      if (t <= 5)      crx_cross(ar, ai, lane, 5 - c, 5 - t, cc, sc);
      else if (c <= 5) crx_local(ar, ai, lane, 5 - c, 7 - t, cc, sc);
      else             rx_pair23(ar, ai, cc, sc);
    }
#pragma unroll
    for (int q = 0; q < 8; ++q) {
      float4 m = sM[base + 16 + q];
      if (q <= 5) gen_cross(ar, ai, lane, 5 - q, m.x, m.y, m.z, m.w);
      else        gen_local(ar, ai, 7 - q, m.x, m.y, m.z, m.w);
    }
    if (2 * h + lp < 3) {   // CRZ diagonal (dropped only at the very end, l==3)
#pragma unroll
      for (int r = 0; r < 4; ++r) {
        float mr = ar[r], mi = ai[r];
        ar[r] = mr*dzr[r] - mi*dzi[r];
        ai[r] = mr*dzi[r] + mi*dzr[r];
      }
    }
  }

  float* Uc = h ? U2c : U1c;
  float4* dst = (float4*)(Uc + (size_t)s0 * 512);
  dst[2*lane]     = make_float4(ar[0], ai[0], ar[1], ai[1]);
  dst[2*lane + 1] = make_float4(ar[2], ai[2], ar[3], ai[3]);
}

// ---------------- K2: U = U2 * U1 (complex), emit bf16 ----------------
// U[i][j] = sum_k U2T[k][i] * U1T[j][k].  Ubf rows: i -> Re, 256+i -> Im.
__global__ __launch_bounds__(256) void combine_u(const float* __restrict__ U1c,
                                                 const float* __restrict__ U2c,
                                                 unsigned short* __restrict__ Ubf) {
  __shared__ float2 S2[32 * 16];   // [kk][i]
  __shared__ float2 S1[16 * 33];   // [j][kk] padded
  const int tid = threadIdx.x;
  const int ti  = tid & 15;
  const int tj  = tid >> 4;
  const int bi  = blockIdx.x & 15;
  const int bj  = blockIdx.x >> 4;

  float accr = 0.f, acci = 0.f;
#pragma unroll 1
  for (int kt = 0; kt < 8; ++kt) {
    __syncthreads();
#pragma unroll
    for (int v = 0; v < 2; ++v) {
      const int s = v * 256 + tid;
      const int k  = s >> 4, i = s & 15;
      S2[k * 16 + i] = *(const float2*)(U2c + (size_t)(kt*32 + k) * 512 + (bi*16 + i) * 2);
      const int j2 = s >> 5, k2 = s & 31;
      S1[j2 * 33 + k2] = *(const float2*)(U1c + (size_t)(bj*16 + j2) * 512 + (kt*32 + k2) * 2);
    }
    __syncthreads();
#pragma unroll
    for (int kk = 0; kk < 32; ++kk) {
      const float2 a = S2[kk * 16 + ti];
      const float2 b = S1[tj * 33 + kk];
      accr = fmaf(a.x, b.x, accr);  accr = fmaf(-a.y, b.y, accr);
      acci = fmaf(a.x, b.y, acci);  acci = fmaf(a.y, b.x, acci);
    }
  }
  const int i = bi * 16 + ti, j = bj * 16 + tj;
  Ubf[(size_t)i * 256 + j]         = f2bf(accr);
  Ubf[(size_t)(i + 256) * 256 + j] = f2bf(acci);
}

// ---------------- K3: amps = U x via MFMA + fused epilogue ----------------
// Block: 16 cols, 4 waves; wave w owns amp rows [w*128, w*128+128).
__global__ __launch_bounds__(256) void mfma_eval(const float* __restrict__ x,
                                                 const unsigned short* __restrict__ Ubf,
                                                 const float* __restrict__ fcw,
                                                 const float* __restrict__ fcb,
                                                 float* __restrict__ out) {
  __shared__ unsigned short Xs[16 * 264];   // [col][k] bf16, padded
  __shared__ float Zp[4][16][9];
  __shared__ float Zf[16][9];
  const int tid  = threadIdx.x;
  const int lane = tid & 63;
  const int w    = tid >> 6;
  const int colbase = blockIdx.x * 16;

  // stage x tile -> bf16 (coalesced reads: 16 consecutive cols per 16 lanes)
#pragma unroll
  for (int pass = 0; pass < 16; ++pass) {
    const int k = pass * 16 + (tid >> 4);
    const int c = tid & 15;
    Xs[c * 264 + k] = f2bf(x[(size_t)k * NSAMP + colbase + c]);
  }
  __syncthreads();

  const int quad = lane >> 4;
  const int n    = lane & 15;
  f32x4 acc[8];
#pragma unroll
  for (int rt = 0; rt < 8; ++rt) acc[rt] = (f32x4){0.f, 0.f, 0.f, 0.f};
  const int rowb = w * 128;

#pragma unroll
  for (int kt = 0; kt < 8; ++kt) {
    const bf16x8 bfrag = *(const bf16x8*)&Xs[n * 264 + kt * 32 + quad * 8];
#pragma unroll
    for (int rt = 0; rt < 8; ++rt) {
      const int row = rowb + rt * 16 + n;
      const bf16x8 afrag = *(const bf16x8*)(Ubf + (size_t)row * 256 + kt * 32 + quad * 8);
      acc[rt] = __builtin_amdgcn_mfma_f32_16x16x32_bf16(afrag, bfrag, acc[rt], 0, 0, 0);
    }
  }

  // epilogue: amp value at (row = w*128 + rt*16 + quad*4 + reg, col = n).
  // s = (w&1)*128 + rt*16 + quad*4 + reg ; sign_q = bit(7-q) of s.
  float za[9];
#pragma unroll
  for (int i = 0; i < 9; ++i) za[i] = 0.f;
  const float m4 = (lane & 32) ? -1.f : 1.f;   // s bit3 = quad bit1
  const float m5 = (lane & 16) ? -1.f : 1.f;   // s bit2 = quad bit0
#pragma unroll
  for (int rt = 0; rt < 8; ++rt) {
#pragma unroll
    for (int reg = 0; reg < 4; ++reg) {
      const float v = acc[rt][reg];
      const float p = v * v;
      za[0] += p;                       // zsum
      za[1] += (w  & 1) ? -p : p;       // q0: s bit7
      za[2] += (rt & 4) ? -p : p;       // q1: s bit6
      za[3] += (rt & 2) ? -p : p;       // q2: s bit5
      za[4] += (rt & 1) ? -p : p;       // q3: s bit4
      za[5] = fmaf(m4, p, za[5]);       // q4
      za[6] = fmaf(m5, p, za[6]);       // q5
      za[7] += (reg & 2) ? -p : p;      // q6: s bit1
      za[8] += (reg & 1) ? -p : p;      // q7: s bit0
    }
  }
  // reduce over quad (lanes sharing col n)
#pragma unroll
  for (int off = 16; off <= 32; off <<= 1) {
#pragma unroll
    for (int i = 0; i < 9; ++i) za[i] += __shfl_xor(za[i], off, 64);
  }
  if (lane < 16) {
#pragma unroll
    for (int i = 0; i < 9; ++i) Zp[w][lane][i] = za[i];
  }
  __syncthreads();

  if (tid < 144) {
    const int col = tid / 9, q = tid - col * 9;
    Zf[col][q] = Zp[0][col][q] + Zp[1][col][q] + Zp[2][col][q] + Zp[3][col][q];
  }
  __syncthreads();

  if (tid < 112) {
    const int col = tid / 7, oo = tid - col * 7;
    const float inv = 1.f / Zf[col][0];
    float v = fcb[oo];
#pragma unroll
    for (int q = 0; q < 8; ++q)
      v = fmaf(fcw[oo * 8 + q], Zf[col][1 + q] * inv, v);
    out[(size_t)(colbase + col) * 7 + oo] = v;
  }
}

extern "C" void kernel_launch(void* const* d_in, const int* in_sizes, int n_in,
                              void* d_out, int out_size, void* d_ws, size_t ws_size,
                              hipStream_t stream) {
  const float* x   = (const float*)d_in[0];   // [256, 4096]
  const float* qw  = (const float*)d_in[1];   // [4, 132]
  const float* fcw = (const float*)d_in[2];   // [7, 8]
  const float* fcb = (const float*)d_in[3];   // [7]
  float* out = (float*)d_out;                 // [4096, 7]

  float* U1c = (float*)d_ws;                      // 256*256 complex fp32 (512 KB)
  float* U2c = U1c + 256 * 512;                   // 512 KB
  unsigned short* Ubf = (unsigned short*)(U2c + 256 * 512);  // 512x256 bf16 (256 KB)

  hipLaunchKernelGGL(build_half, dim3(512), dim3(64),  0, stream, qw, U1c, U2c);
  hipLaunchKernelGGL(combine_u,  dim3(256), dim3(256), 0, stream, U1c, U2c, Ubf);
  hipLaunchKernelGGL(mfma_eval,  dim3(256), dim3(256), 0, stream, x, Ubf, fcw, fcb, out);
}